// Round 1
// baseline (1849.918 us; speedup 1.0000x reference)
//
#include <hip/hip_runtime.h>
#include <hip/hip_bf16.h>
#include <math.h>

// ---------------------------------------------------------------------------
// GCN GraphRegressor: 3x (linear -> gather*norm -> scatter-sum -> relu)
//                     -> segment-mean pool -> MLP head
// Strategy: build dst-CSR once (atomic count + 1-block scan + cursor fill),
// then each layer is GEMM (fp32 vector ALU) + gather-aggregate (no atomics).
// ---------------------------------------------------------------------------

__global__ void count_deg_kernel(const int* __restrict__ dst, int* __restrict__ indeg, int E) {
  int e = blockIdx.x * 256 + threadIdx.x;
  if (e < E) atomicAdd(&indeg[dst[e]], 1);
}

// exclusive scan of (indeg[i]+1) into ptr[0..n], single block of 1024
__global__ void scan_kernel(const int* __restrict__ indeg, int* __restrict__ ptr, int n) {
  __shared__ int smem[1024];
  __shared__ int carry_s;
  if (threadIdx.x == 0) carry_s = 0;
  __syncthreads();
  for (int base = 0; base < n; base += 1024) {
    int i = base + threadIdx.x;
    int v = (i < n) ? (indeg[i] + 1) : 0;
    smem[threadIdx.x] = v;
    __syncthreads();
    for (int off = 1; off < 1024; off <<= 1) {
      int t = 0;
      if (threadIdx.x >= off) t = smem[threadIdx.x - off];
      __syncthreads();
      if (threadIdx.x >= off) smem[threadIdx.x] += t;
      __syncthreads();
    }
    if (i < n) ptr[i] = carry_s + smem[threadIdx.x] - v;  // exclusive
    __syncthreads();
    if (threadIdx.x == 1023) carry_s += smem[1023];
    __syncthreads();
  }
  if (threadIdx.x == 0) ptr[n] = carry_s;
}

__global__ void fill_edges_kernel(const int* __restrict__ src, const int* __restrict__ dst,
                                  const int* __restrict__ indeg, const int* __restrict__ ptr,
                                  int* __restrict__ cursor, int* __restrict__ csrc,
                                  float* __restrict__ cnorm, int E) {
  int e = blockIdx.x * 256 + threadIdx.x;
  if (e >= E) return;
  int s = src[e], d = dst[e];
  int pos = ptr[d] + atomicAdd(&cursor[d], 1);
  csrc[pos] = s;
  float dd = (float)(indeg[s] + 1) * (float)(indeg[d] + 1);
  cnorm[pos] = 1.0f / sqrtf(dd);
}

__global__ void fill_self_kernel(const int* __restrict__ indeg, const int* __restrict__ ptr,
                                 int* __restrict__ cursor, int* __restrict__ csrc,
                                 float* __restrict__ cnorm, int n) {
  int i = blockIdx.x * 256 + threadIdx.x;
  if (i >= n) return;
  int pos = ptr[i] + atomicAdd(&cursor[i], 1);
  csrc[pos] = i;
  cnorm[pos] = 1.0f / (float)(indeg[i] + 1);
}

// H[n,128] = X[n,128] @ W[128,128] + bias ; thread = 2 rows x 8 cols
__global__ __launch_bounds__(256) void gemm_bias_kernel(
    const float* __restrict__ X, const float* __restrict__ W,
    const float* __restrict__ bias, float* __restrict__ H, int n) {
  int t = threadIdx.x;
  int col0 = (t & 15) * 8;
  int row0 = blockIdx.x * 32 + (t >> 4) * 2;
  int r0 = min(row0, n - 1);
  int r1 = min(row0 + 1, n - 1);
  const float* x0p = X + (size_t)r0 * 128;
  const float* x1p = X + (size_t)r1 * 128;
  float a0[8] = {0.f, 0.f, 0.f, 0.f, 0.f, 0.f, 0.f, 0.f};
  float a1[8] = {0.f, 0.f, 0.f, 0.f, 0.f, 0.f, 0.f, 0.f};
#pragma unroll 4
  for (int k = 0; k < 128; ++k) {
    float xv0 = x0p[k];
    float xv1 = x1p[k];
    float4 wa = *(const float4*)(W + k * 128 + col0);
    float4 wb = *(const float4*)(W + k * 128 + col0 + 4);
    a0[0] = fmaf(xv0, wa.x, a0[0]); a0[1] = fmaf(xv0, wa.y, a0[1]);
    a0[2] = fmaf(xv0, wa.z, a0[2]); a0[3] = fmaf(xv0, wa.w, a0[3]);
    a0[4] = fmaf(xv0, wb.x, a0[4]); a0[5] = fmaf(xv0, wb.y, a0[5]);
    a0[6] = fmaf(xv0, wb.z, a0[6]); a0[7] = fmaf(xv0, wb.w, a0[7]);
    a1[0] = fmaf(xv1, wa.x, a1[0]); a1[1] = fmaf(xv1, wa.y, a1[1]);
    a1[2] = fmaf(xv1, wa.z, a1[2]); a1[3] = fmaf(xv1, wa.w, a1[3]);
    a1[4] = fmaf(xv1, wb.x, a1[4]); a1[5] = fmaf(xv1, wb.y, a1[5]);
    a1[6] = fmaf(xv1, wb.z, a1[6]); a1[7] = fmaf(xv1, wb.w, a1[7]);
  }
  float4 ba = *(const float4*)(bias + col0);
  float4 bb = *(const float4*)(bias + col0 + 4);
  if (row0 < n) {
    float4 o0 = {a0[0] + ba.x, a0[1] + ba.y, a0[2] + ba.z, a0[3] + ba.w};
    float4 o1 = {a0[4] + bb.x, a0[5] + bb.y, a0[6] + bb.z, a0[7] + bb.w};
    *(float4*)(H + (size_t)row0 * 128 + col0) = o0;
    *(float4*)(H + (size_t)row0 * 128 + col0 + 4) = o1;
  }
  if (row0 + 1 < n) {
    float4 o0 = {a1[0] + ba.x, a1[1] + ba.y, a1[2] + ba.z, a1[3] + ba.w};
    float4 o1 = {a1[4] + bb.x, a1[5] + bb.y, a1[6] + bb.z, a1[7] + bb.w};
    *(float4*)(H + (size_t)(row0 + 1) * 128 + col0) = o0;
    *(float4*)(H + (size_t)(row0 + 1) * 128 + col0 + 4) = o1;
  }
}

// Xout[node,c] = relu( sum_{e in CSR[node]} H[csrc[e], c] * cnorm[e] )
__global__ __launch_bounds__(256) void aggregate_kernel(
    const float* __restrict__ H, const int* __restrict__ ptr,
    const int* __restrict__ csrc, const float* __restrict__ cnorm,
    float* __restrict__ Xout, int n) {
  int node = blockIdx.x * 2 + (threadIdx.x >> 7);
  int c = threadIdx.x & 127;
  if (node >= n) return;
  int beg = ptr[node], end = ptr[node + 1];
  float acc = 0.f;
  for (int e = beg; e < end; ++e) {
    int s = csrc[e];
    float nm = cnorm[e];
    acc = fmaf(H[(size_t)s * 128 + c], nm, acc);
  }
  Xout[(size_t)node * 128 + c] = fmaxf(acc, 0.f);
}

__global__ __launch_bounds__(256) void pool_kernel(
    const float* __restrict__ X, const int* __restrict__ batch,
    float* __restrict__ pool, float* __restrict__ cnt, int n) {
  int node = blockIdx.x * 2 + (threadIdx.x >> 7);
  int c = threadIdx.x & 127;
  if (node >= n) return;
  int g = batch[node];
  atomicAdd(&pool[(size_t)g * 128 + c], X[(size_t)node * 128 + c]);
  if (c == 0) atomicAdd(&cnt[g], 1.0f);
}

__global__ __launch_bounds__(128) void head_kernel(
    const float* __restrict__ pool, const float* __restrict__ cnt,
    const float* __restrict__ Wp1, const float* __restrict__ bp1,
    const float* __restrict__ Wp2, const float* __restrict__ bp2,
    float* __restrict__ out, int G) {
  int g = blockIdx.x;
  int j = threadIdx.x;
  __shared__ float ps[128];
  __shared__ float hs[128];
  float inv = 1.0f / fmaxf(cnt[g], 1.0f);
  ps[j] = pool[(size_t)g * 128 + j] * inv;
  __syncthreads();
  float acc = bp1[j];
#pragma unroll 8
  for (int k = 0; k < 128; ++k) acc = fmaf(ps[k], Wp1[k * 128 + j], acc);
  hs[j] = fmaxf(acc, 0.f) * Wp2[j];
  __syncthreads();
  for (int off = 64; off > 0; off >>= 1) {
    if (j < off) hs[j] += hs[j + off];
    __syncthreads();
  }
  if (j == 0) out[g] = hs[0] + bp2[0];
}

extern "C" void kernel_launch(void* const* d_in, const int* in_sizes, int n_in,
                              void* d_out, int out_size, void* d_ws, size_t ws_size,
                              hipStream_t stream) {
  const float* x    = (const float*)d_in[0];
  const int*   eidx = (const int*)d_in[1];
  const int*   batch= (const int*)d_in[2];
  const float* W0 = (const float*)d_in[3];
  const float* b0 = (const float*)d_in[4];
  const float* W1 = (const float*)d_in[5];
  const float* b1 = (const float*)d_in[6];
  const float* W2 = (const float*)d_in[7];
  const float* b2 = (const float*)d_in[8];
  const float* Wp1 = (const float*)d_in[9];
  const float* bp1 = (const float*)d_in[10];
  const float* Wp2 = (const float*)d_in[11];
  const float* bp2 = (const float*)d_in[12];
  float* out = (float*)d_out;

  const int N = in_sizes[0] / 128;
  const int E = in_sizes[1] / 2;
  const int G = out_size;
  const int M = E + N;

  const int* src = eidx;
  const int* dst = eidx + E;

  char* ws = (char*)d_ws;
  size_t off = 0;
  auto alloc = [&](size_t bytes) -> void* {
    void* p = ws + off;
    off = (off + bytes + 255) & ~(size_t)255;
    return p;
  };
  int*   indeg  = (int*)  alloc((size_t)N * 4);
  int*   ptr    = (int*)  alloc((size_t)(N + 1) * 4);
  int*   cursor = (int*)  alloc((size_t)N * 4);
  int*   csrc   = (int*)  alloc((size_t)M * 4);
  float* cnorm  = (float*)alloc((size_t)M * 4);
  float* bufH   = (float*)alloc((size_t)N * 128 * 4);
  float* bufX   = (float*)alloc((size_t)N * 128 * 4);
  float* pool   = (float*)alloc((size_t)G * 128 * 4);
  float* cnt    = (float*)alloc((size_t)G * 4);
  (void)ws_size;

  hipMemsetAsync(indeg,  0, (size_t)N * 4, stream);
  hipMemsetAsync(cursor, 0, (size_t)N * 4, stream);
  hipMemsetAsync(pool,   0, (size_t)G * 128 * 4, stream);
  hipMemsetAsync(cnt,    0, (size_t)G * 4, stream);

  count_deg_kernel<<<(E + 255) / 256, 256, 0, stream>>>(dst, indeg, E);
  scan_kernel<<<1, 1024, 0, stream>>>(indeg, ptr, N);
  fill_edges_kernel<<<(E + 255) / 256, 256, 0, stream>>>(src, dst, indeg, ptr, cursor, csrc, cnorm, E);
  fill_self_kernel<<<(N + 255) / 256, 256, 0, stream>>>(indeg, ptr, cursor, csrc, cnorm, N);

  dim3 gemm_grid((N + 31) / 32);
  dim3 node_grid((N + 1) / 2);

  gemm_bias_kernel<<<gemm_grid, 256, 0, stream>>>(x,    W0, b0, bufH, N);
  aggregate_kernel<<<node_grid, 256, 0, stream>>>(bufH, ptr, csrc, cnorm, bufX, N);
  gemm_bias_kernel<<<gemm_grid, 256, 0, stream>>>(bufX, W1, b1, bufH, N);
  aggregate_kernel<<<node_grid, 256, 0, stream>>>(bufH, ptr, csrc, cnorm, bufX, N);
  gemm_bias_kernel<<<gemm_grid, 256, 0, stream>>>(bufX, W2, b2, bufH, N);
  aggregate_kernel<<<node_grid, 256, 0, stream>>>(bufH, ptr, csrc, cnorm, bufX, N);

  pool_kernel<<<node_grid, 256, 0, stream>>>(bufX, batch, pool, cnt, N);
  head_kernel<<<G, 128, 0, stream>>>(pool, cnt, Wp1, bp1, Wp2, bp2, out, G);
}

// Round 2
// 1017.933 us; speedup vs baseline: 1.8173x; 1.8173x over previous
//
#include <hip/hip_runtime.h>
#include <hip/hip_bf16.h>
#include <math.h>

// ---------------------------------------------------------------------------
// GCN GraphRegressor: 3x (linear -> gather*norm -> scatter-sum -> relu)
//                     -> segment-mean pool -> MLP head
// R2: aggregate = 1 wave/node, shfl-broadcast edge metadata, 4-way unrolled
//     independent gathers (breaks the dependent-load latency chain).
//     GEMM = 4 rows x 8 cols per thread, float4 k-chunks.
//     Multi-block 3-phase scan; layer-3 aggregate fused with pool.
// ---------------------------------------------------------------------------

__global__ void count_deg_kernel(const int* __restrict__ dst, int* __restrict__ indeg, int E) {
  int e = blockIdx.x * 256 + threadIdx.x;
  if (e < E) atomicAdd(&indeg[dst[e]], 1);
}

// ---- 3-phase exclusive scan of (indeg[i]+1) into ptr[0..n] ----------------
// phase 1: per-tile (1024 elems) sums
__global__ __launch_bounds__(1024) void tile_reduce_kernel(
    const int* __restrict__ indeg, int* __restrict__ tilesum, int n) {
  __shared__ int ws[16];
  int i = blockIdx.x * 1024 + threadIdx.x;
  int v = (i < n) ? (indeg[i] + 1) : 0;
  for (int off = 32; off > 0; off >>= 1) v += __shfl_down(v, off);
  int wid = threadIdx.x >> 6, lane = threadIdx.x & 63;
  if (lane == 0) ws[wid] = v;
  __syncthreads();
  if (threadIdx.x == 0) {
    int s = 0;
    for (int w = 0; w < 16; ++w) s += ws[w];
    tilesum[blockIdx.x] = s;
  }
}

// phase 2: exclusive scan of tile sums (T <= 128), one block of 128
__global__ __launch_bounds__(128) void scan_tiles_kernel(
    const int* __restrict__ tilesum, int* __restrict__ tileoff,
    int* __restrict__ ptr_last, int T) {
  __shared__ int sm[128];
  int v = (threadIdx.x < T) ? tilesum[threadIdx.x] : 0;
  sm[threadIdx.x] = v;
  __syncthreads();
  for (int off = 1; off < 128; off <<= 1) {
    int t = (threadIdx.x >= off) ? sm[threadIdx.x - off] : 0;
    __syncthreads();
    sm[threadIdx.x] += t;
    __syncthreads();
  }
  if (threadIdx.x < T) tileoff[threadIdx.x] = sm[threadIdx.x] - v;
  if (threadIdx.x == 127) *ptr_last = sm[127];
}

// phase 3: per-tile block scan + tile offset -> exclusive ptr[i]
__global__ __launch_bounds__(1024) void scan_emit_kernel(
    const int* __restrict__ indeg, const int* __restrict__ tileoff,
    int* __restrict__ ptr, int n) {
  __shared__ int wsum[16];
  int i = blockIdx.x * 1024 + threadIdx.x;
  int v = (i < n) ? (indeg[i] + 1) : 0;
  int lane = threadIdx.x & 63, wid = threadIdx.x >> 6;
  int x = v;
  for (int off = 1; off < 64; off <<= 1) {
    int y = __shfl_up(x, off);
    if (lane >= off) x += y;
  }
  if (lane == 63) wsum[wid] = x;
  __syncthreads();
  if (threadIdx.x == 0) {
    int run = 0;
    for (int w = 0; w < 16; ++w) { int t = wsum[w]; wsum[w] = run; run += t; }
  }
  __syncthreads();
  if (i < n) ptr[i] = x - v + wsum[wid] + tileoff[blockIdx.x];
}

__global__ void fill_edges_kernel(const int* __restrict__ src, const int* __restrict__ dst,
                                  const int* __restrict__ indeg, const int* __restrict__ ptr,
                                  int* __restrict__ cursor, int* __restrict__ csrc,
                                  float* __restrict__ cnorm, int E) {
  int e = blockIdx.x * 256 + threadIdx.x;
  if (e >= E) return;
  int s = src[e], d = dst[e];
  int pos = ptr[d] + atomicAdd(&cursor[d], 1);
  csrc[pos] = s;
  float dd = (float)(indeg[s] + 1) * (float)(indeg[d] + 1);
  cnorm[pos] = 1.0f / sqrtf(dd);
}

__global__ void fill_self_kernel(const int* __restrict__ indeg, const int* __restrict__ ptr,
                                 int* __restrict__ cursor, int* __restrict__ csrc,
                                 float* __restrict__ cnorm, int n) {
  int i = blockIdx.x * 256 + threadIdx.x;
  if (i >= n) return;
  int pos = ptr[i] + atomicAdd(&cursor[i], 1);
  csrc[pos] = i;
  cnorm[pos] = 1.0f / (float)(indeg[i] + 1);
}

// H[n,128] = X[n,128] @ W[128,128] + bias ; thread = 4 rows x 8 cols, k by 4
__global__ __launch_bounds__(256) void gemm_bias_kernel(
    const float* __restrict__ X, const float* __restrict__ W,
    const float* __restrict__ bias, float* __restrict__ H, int n) {
  int t = threadIdx.x;
  int col0 = (t & 15) * 8;
  int rbase = blockIdx.x * 64 + (t >> 4) * 4;
  const float* xp0 = X + (size_t)min(rbase + 0, n - 1) * 128;
  const float* xp1 = X + (size_t)min(rbase + 1, n - 1) * 128;
  const float* xp2 = X + (size_t)min(rbase + 2, n - 1) * 128;
  const float* xp3 = X + (size_t)min(rbase + 3, n - 1) * 128;
  float acc[4][8];
#pragma unroll
  for (int r = 0; r < 4; ++r)
#pragma unroll
    for (int c = 0; c < 8; ++c) acc[r][c] = 0.f;

  for (int k = 0; k < 128; k += 4) {
    float4 xv[4];
    xv[0] = *(const float4*)(xp0 + k);
    xv[1] = *(const float4*)(xp1 + k);
    xv[2] = *(const float4*)(xp2 + k);
    xv[3] = *(const float4*)(xp3 + k);
#pragma unroll
    for (int kk = 0; kk < 4; ++kk) {
      const float* wrow = W + (size_t)(k + kk) * 128 + col0;
      float4 wa = *(const float4*)(wrow);
      float4 wb = *(const float4*)(wrow + 4);
#pragma unroll
      for (int r = 0; r < 4; ++r) {
        float xs = ((const float*)&xv[r])[kk];
        acc[r][0] = fmaf(xs, wa.x, acc[r][0]);
        acc[r][1] = fmaf(xs, wa.y, acc[r][1]);
        acc[r][2] = fmaf(xs, wa.z, acc[r][2]);
        acc[r][3] = fmaf(xs, wa.w, acc[r][3]);
        acc[r][4] = fmaf(xs, wb.x, acc[r][4]);
        acc[r][5] = fmaf(xs, wb.y, acc[r][5]);
        acc[r][6] = fmaf(xs, wb.z, acc[r][6]);
        acc[r][7] = fmaf(xs, wb.w, acc[r][7]);
      }
    }
  }
  float4 ba = *(const float4*)(bias + col0);
  float4 bb = *(const float4*)(bias + col0 + 4);
#pragma unroll
  for (int r = 0; r < 4; ++r) {
    int row = rbase + r;
    if (row < n) {
      float4 o0 = {acc[r][0] + ba.x, acc[r][1] + ba.y, acc[r][2] + ba.z, acc[r][3] + ba.w};
      float4 o1 = {acc[r][4] + bb.x, acc[r][5] + bb.y, acc[r][6] + bb.z, acc[r][7] + bb.w};
      *(float4*)(H + (size_t)row * 128 + col0) = o0;
      *(float4*)(H + (size_t)row * 128 + col0 + 4) = o1;
    }
  }
}

// Core of the aggregate: one wave per node, lane holds 2 channels (float2).
// Edge metadata preloaded 64-at-a-time in one coalesced load, broadcast via
// __shfl; 4 independent accumulators so the 4 gathers per step pipeline.
__device__ __forceinline__ float2 aggregate_node(
    const float* __restrict__ H, const int* __restrict__ csrc,
    const float* __restrict__ cnorm, int beg, int end, int lane) {
  float2 a0 = {0.f, 0.f}, a1 = {0.f, 0.f}, a2 = {0.f, 0.f}, a3 = {0.f, 0.f};
  const float* Hc = H + lane * 2;
  for (int base = beg; base < end; base += 64) {
    int m = end - base;
    if (m > 64) m = 64;
    int idx = base + lane;
    int sl = (lane < m) ? csrc[idx] : 0;
    float nl = (lane < m) ? cnorm[idx] : 0.f;
    int j = 0;
    for (; j + 3 < m; j += 4) {
      int s0 = __shfl(sl, j), s1 = __shfl(sl, j + 1);
      int s2 = __shfl(sl, j + 2), s3 = __shfl(sl, j + 3);
      float n0 = __shfl(nl, j), n1 = __shfl(nl, j + 1);
      float n2 = __shfl(nl, j + 2), n3 = __shfl(nl, j + 3);
      float2 h0 = *(const float2*)(Hc + (size_t)s0 * 128);
      float2 h1 = *(const float2*)(Hc + (size_t)s1 * 128);
      float2 h2 = *(const float2*)(Hc + (size_t)s2 * 128);
      float2 h3 = *(const float2*)(Hc + (size_t)s3 * 128);
      a0.x = fmaf(h0.x, n0, a0.x); a0.y = fmaf(h0.y, n0, a0.y);
      a1.x = fmaf(h1.x, n1, a1.x); a1.y = fmaf(h1.y, n1, a1.y);
      a2.x = fmaf(h2.x, n2, a2.x); a2.y = fmaf(h2.y, n2, a2.y);
      a3.x = fmaf(h3.x, n3, a3.x); a3.y = fmaf(h3.y, n3, a3.y);
    }
    for (; j < m; ++j) {
      int s0 = __shfl(sl, j);
      float n0 = __shfl(nl, j);
      float2 h0 = *(const float2*)(Hc + (size_t)s0 * 128);
      a0.x = fmaf(h0.x, n0, a0.x); a0.y = fmaf(h0.y, n0, a0.y);
    }
  }
  float2 o;
  o.x = fmaxf((a0.x + a1.x) + (a2.x + a3.x), 0.f);
  o.y = fmaxf((a0.y + a1.y) + (a2.y + a3.y), 0.f);
  return o;
}

__global__ __launch_bounds__(256) void aggregate_kernel(
    const float* __restrict__ H, const int* __restrict__ ptr,
    const int* __restrict__ csrc, const float* __restrict__ cnorm,
    float* __restrict__ Xout, int n) {
  int node = blockIdx.x * 4 + (threadIdx.x >> 6);
  if (node >= n) return;
  int lane = threadIdx.x & 63;
  int beg = ptr[node], end = ptr[node + 1];
  float2 o = aggregate_node(H, csrc, cnorm, beg, end, lane);
  *(float2*)(Xout + (size_t)node * 128 + lane * 2) = o;
}

// layer-3 aggregate fused with segment-sum pool (atomic)
__global__ __launch_bounds__(256) void aggregate_pool_kernel(
    const float* __restrict__ H, const int* __restrict__ ptr,
    const int* __restrict__ csrc, const float* __restrict__ cnorm,
    const int* __restrict__ batch, float* __restrict__ pool,
    float* __restrict__ cnt, int n) {
  int node = blockIdx.x * 4 + (threadIdx.x >> 6);
  if (node >= n) return;
  int lane = threadIdx.x & 63;
  int beg = ptr[node], end = ptr[node + 1];
  float2 o = aggregate_node(H, csrc, cnorm, beg, end, lane);
  int g = batch[node];
  atomicAdd(&pool[(size_t)g * 128 + lane * 2], o.x);
  atomicAdd(&pool[(size_t)g * 128 + lane * 2 + 1], o.y);
  if (lane == 0) atomicAdd(&cnt[g], 1.0f);
}

__global__ __launch_bounds__(128) void head_kernel(
    const float* __restrict__ pool, const float* __restrict__ cnt,
    const float* __restrict__ Wp1, const float* __restrict__ bp1,
    const float* __restrict__ Wp2, const float* __restrict__ bp2,
    float* __restrict__ out, int G) {
  int g = blockIdx.x;
  int j = threadIdx.x;
  __shared__ float ps[128];
  __shared__ float hs[128];
  float inv = 1.0f / fmaxf(cnt[g], 1.0f);
  ps[j] = pool[(size_t)g * 128 + j] * inv;
  __syncthreads();
  float acc = bp1[j];
#pragma unroll 8
  for (int k = 0; k < 128; ++k) acc = fmaf(ps[k], Wp1[k * 128 + j], acc);
  hs[j] = fmaxf(acc, 0.f) * Wp2[j];
  __syncthreads();
  for (int off = 64; off > 0; off >>= 1) {
    if (j < off) hs[j] += hs[j + off];
    __syncthreads();
  }
  if (j == 0) out[g] = hs[0] + bp2[0];
}

extern "C" void kernel_launch(void* const* d_in, const int* in_sizes, int n_in,
                              void* d_out, int out_size, void* d_ws, size_t ws_size,
                              hipStream_t stream) {
  const float* x    = (const float*)d_in[0];
  const int*   eidx = (const int*)d_in[1];
  const int*   batch= (const int*)d_in[2];
  const float* W0 = (const float*)d_in[3];
  const float* b0 = (const float*)d_in[4];
  const float* W1 = (const float*)d_in[5];
  const float* b1 = (const float*)d_in[6];
  const float* W2 = (const float*)d_in[7];
  const float* b2 = (const float*)d_in[8];
  const float* Wp1 = (const float*)d_in[9];
  const float* bp1 = (const float*)d_in[10];
  const float* Wp2 = (const float*)d_in[11];
  const float* bp2 = (const float*)d_in[12];
  float* out = (float*)d_out;

  const int N = in_sizes[0] / 128;
  const int E = in_sizes[1] / 2;
  const int G = out_size;
  const int M = E + N;
  const int T = (N + 1023) / 1024;  // #scan tiles; N<=131072 keeps T<=128

  const int* src = eidx;
  const int* dst = eidx + E;

  char* ws = (char*)d_ws;
  size_t off = 0;
  auto alloc = [&](size_t bytes) -> void* {
    void* p = ws + off;
    off = (off + bytes + 255) & ~(size_t)255;
    return p;
  };
  int*   indeg   = (int*)  alloc((size_t)N * 4);
  int*   ptr     = (int*)  alloc((size_t)(N + 1) * 4);
  int*   cursor  = (int*)  alloc((size_t)N * 4);
  int*   csrc    = (int*)  alloc((size_t)M * 4);
  float* cnorm   = (float*)alloc((size_t)M * 4);
  float* bufH    = (float*)alloc((size_t)N * 128 * 4);
  float* bufX    = (float*)alloc((size_t)N * 128 * 4);
  float* pool    = (float*)alloc((size_t)G * 128 * 4);
  float* cnt     = (float*)alloc((size_t)G * 4);
  int*   tilesum = (int*)  alloc((size_t)T * 4);
  int*   tileoff = (int*)  alloc((size_t)T * 4);
  (void)ws_size;

  hipMemsetAsync(indeg,  0, (size_t)N * 4, stream);
  hipMemsetAsync(cursor, 0, (size_t)N * 4, stream);
  hipMemsetAsync(pool,   0, (size_t)G * 128 * 4, stream);
  hipMemsetAsync(cnt,    0, (size_t)G * 4, stream);

  count_deg_kernel<<<(E + 255) / 256, 256, 0, stream>>>(dst, indeg, E);
  tile_reduce_kernel<<<T, 1024, 0, stream>>>(indeg, tilesum, N);
  scan_tiles_kernel<<<1, 128, 0, stream>>>(tilesum, tileoff, ptr + N, T);
  scan_emit_kernel<<<T, 1024, 0, stream>>>(indeg, tileoff, ptr, N);
  fill_edges_kernel<<<(E + 255) / 256, 256, 0, stream>>>(src, dst, indeg, ptr, cursor, csrc, cnorm, E);
  fill_self_kernel<<<(N + 255) / 256, 256, 0, stream>>>(indeg, ptr, cursor, csrc, cnorm, N);

  dim3 gemm_grid((N + 63) / 64);
  dim3 node_grid((N + 3) / 4);

  gemm_bias_kernel<<<gemm_grid, 256, 0, stream>>>(x,    W0, b0, bufH, N);
  aggregate_kernel<<<node_grid, 256, 0, stream>>>(bufH, ptr, csrc, cnorm, bufX, N);
  gemm_bias_kernel<<<gemm_grid, 256, 0, stream>>>(bufX, W1, b1, bufH, N);
  aggregate_kernel<<<node_grid, 256, 0, stream>>>(bufH, ptr, csrc, cnorm, bufX, N);
  gemm_bias_kernel<<<gemm_grid, 256, 0, stream>>>(bufX, W2, b2, bufH, N);
  aggregate_pool_kernel<<<node_grid, 256, 0, stream>>>(bufH, ptr, csrc, cnorm, batch, pool, cnt, N);

  head_kernel<<<G, 128, 0, stream>>>(pool, cnt, Wp1, bp1, Wp2, bp2, out, G);
}

// Round 3
// 920.104 us; speedup vs baseline: 2.0106x; 1.1063x over previous
//
#include <hip/hip_runtime.h>
#include <hip/hip_bf16.h>
#include <math.h>

// ---------------------------------------------------------------------------
// GCN GraphRegressor: 3x (linear -> gather*norm -> scatter-sum -> relu)
//                     -> segment-mean pool -> MLP head
// R3: aggregate = HALF-wave per node, lane = 4 channels (float4 gathers),
//     2 independent edge streams/wave x 4-deep unroll = 8 loads in flight.
//     Pool: atomic-free segmented reduction (batch is sorted) fused with the
//     MLP head, one block per graph. No pool/cnt atomics at all.
// ---------------------------------------------------------------------------

__global__ void count_deg_kernel(const int* __restrict__ dst, int* __restrict__ indeg, int E) {
  int e = blockIdx.x * 256 + threadIdx.x;
  if (e < E) atomicAdd(&indeg[dst[e]], 1);
}

// ---- 3-phase exclusive scan of (indeg[i]+1) into ptr[0..n] ----------------
__global__ __launch_bounds__(1024) void tile_reduce_kernel(
    const int* __restrict__ indeg, int* __restrict__ tilesum, int n) {
  __shared__ int ws[16];
  int i = blockIdx.x * 1024 + threadIdx.x;
  int v = (i < n) ? (indeg[i] + 1) : 0;
  for (int off = 32; off > 0; off >>= 1) v += __shfl_down(v, off);
  int wid = threadIdx.x >> 6, lane = threadIdx.x & 63;
  if (lane == 0) ws[wid] = v;
  __syncthreads();
  if (threadIdx.x == 0) {
    int s = 0;
    for (int w = 0; w < 16; ++w) s += ws[w];
    tilesum[blockIdx.x] = s;
  }
}

__global__ __launch_bounds__(128) void scan_tiles_kernel(
    const int* __restrict__ tilesum, int* __restrict__ tileoff,
    int* __restrict__ ptr_last, int T) {
  __shared__ int sm[128];
  int v = (threadIdx.x < T) ? tilesum[threadIdx.x] : 0;
  sm[threadIdx.x] = v;
  __syncthreads();
  for (int off = 1; off < 128; off <<= 1) {
    int t = (threadIdx.x >= off) ? sm[threadIdx.x - off] : 0;
    __syncthreads();
    sm[threadIdx.x] += t;
    __syncthreads();
  }
  if (threadIdx.x < T) tileoff[threadIdx.x] = sm[threadIdx.x] - v;
  if (threadIdx.x == 127) *ptr_last = sm[127];
}

__global__ __launch_bounds__(1024) void scan_emit_kernel(
    const int* __restrict__ indeg, const int* __restrict__ tileoff,
    int* __restrict__ ptr, int n) {
  __shared__ int wsum[16];
  int i = blockIdx.x * 1024 + threadIdx.x;
  int v = (i < n) ? (indeg[i] + 1) : 0;
  int lane = threadIdx.x & 63, wid = threadIdx.x >> 6;
  int x = v;
  for (int off = 1; off < 64; off <<= 1) {
    int y = __shfl_up(x, off);
    if (lane >= off) x += y;
  }
  if (lane == 63) wsum[wid] = x;
  __syncthreads();
  if (threadIdx.x == 0) {
    int run = 0;
    for (int w = 0; w < 16; ++w) { int t = wsum[w]; wsum[w] = run; run += t; }
  }
  __syncthreads();
  if (i < n) ptr[i] = x - v + wsum[wid] + tileoff[blockIdx.x];
}

__global__ void fill_edges_kernel(const int* __restrict__ src, const int* __restrict__ dst,
                                  const int* __restrict__ indeg, const int* __restrict__ ptr,
                                  int* __restrict__ cursor, int* __restrict__ csrc,
                                  float* __restrict__ cnorm, int E) {
  int e = blockIdx.x * 256 + threadIdx.x;
  if (e >= E) return;
  int s = src[e], d = dst[e];
  int pos = ptr[d] + atomicAdd(&cursor[d], 1);
  csrc[pos] = s;
  float dd = (float)(indeg[s] + 1) * (float)(indeg[d] + 1);
  cnorm[pos] = 1.0f / sqrtf(dd);
}

__global__ void fill_self_kernel(const int* __restrict__ indeg, const int* __restrict__ ptr,
                                 int* __restrict__ cursor, int* __restrict__ csrc,
                                 float* __restrict__ cnorm, int n) {
  int i = blockIdx.x * 256 + threadIdx.x;
  if (i >= n) return;
  int pos = ptr[i] + atomicAdd(&cursor[i], 1);
  csrc[pos] = i;
  cnorm[pos] = 1.0f / (float)(indeg[i] + 1);
}

// graph boundaries from sorted batch: gptr[g] = first node with batch >= g
__global__ void graph_bounds_kernel(const int* __restrict__ batch,
                                    int* __restrict__ gptr, int n, int G) {
  int i = blockIdx.x * 256 + threadIdx.x;
  if (i >= n) return;
  int b = batch[i];
  if (i == 0) {
    for (int g = 0; g <= b; ++g) gptr[g] = 0;
  } else {
    int bp = batch[i - 1];
    for (int g = bp + 1; g <= b; ++g) gptr[g] = i;
  }
  if (i == n - 1) {
    for (int g = b + 1; g <= G; ++g) gptr[g] = n;
  }
}

// H[n,128] = X[n,128] @ W[128,128] + bias ; thread = 4 rows x 8 cols, k by 4
__global__ __launch_bounds__(256) void gemm_bias_kernel(
    const float* __restrict__ X, const float* __restrict__ W,
    const float* __restrict__ bias, float* __restrict__ H, int n) {
  int t = threadIdx.x;
  int col0 = (t & 15) * 8;
  int rbase = blockIdx.x * 64 + (t >> 4) * 4;
  const float* xp0 = X + (size_t)min(rbase + 0, n - 1) * 128;
  const float* xp1 = X + (size_t)min(rbase + 1, n - 1) * 128;
  const float* xp2 = X + (size_t)min(rbase + 2, n - 1) * 128;
  const float* xp3 = X + (size_t)min(rbase + 3, n - 1) * 128;
  float acc[4][8];
#pragma unroll
  for (int r = 0; r < 4; ++r)
#pragma unroll
    for (int c = 0; c < 8; ++c) acc[r][c] = 0.f;

  for (int k = 0; k < 128; k += 4) {
    float4 xv[4];
    xv[0] = *(const float4*)(xp0 + k);
    xv[1] = *(const float4*)(xp1 + k);
    xv[2] = *(const float4*)(xp2 + k);
    xv[3] = *(const float4*)(xp3 + k);
#pragma unroll
    for (int kk = 0; kk < 4; ++kk) {
      const float* wrow = W + (size_t)(k + kk) * 128 + col0;
      float4 wa = *(const float4*)(wrow);
      float4 wb = *(const float4*)(wrow + 4);
#pragma unroll
      for (int r = 0; r < 4; ++r) {
        float xs = ((const float*)&xv[r])[kk];
        acc[r][0] = fmaf(xs, wa.x, acc[r][0]);
        acc[r][1] = fmaf(xs, wa.y, acc[r][1]);
        acc[r][2] = fmaf(xs, wa.z, acc[r][2]);
        acc[r][3] = fmaf(xs, wa.w, acc[r][3]);
        acc[r][4] = fmaf(xs, wb.x, acc[r][4]);
        acc[r][5] = fmaf(xs, wb.y, acc[r][5]);
        acc[r][6] = fmaf(xs, wb.z, acc[r][6]);
        acc[r][7] = fmaf(xs, wb.w, acc[r][7]);
      }
    }
  }
  float4 ba = *(const float4*)(bias + col0);
  float4 bb = *(const float4*)(bias + col0 + 4);
#pragma unroll
  for (int r = 0; r < 4; ++r) {
    int row = rbase + r;
    if (row < n) {
      float4 o0 = {acc[r][0] + ba.x, acc[r][1] + ba.y, acc[r][2] + ba.z, acc[r][3] + ba.w};
      float4 o1 = {acc[r][4] + bb.x, acc[r][5] + bb.y, acc[r][6] + bb.z, acc[r][7] + bb.w};
      *(float4*)(H + (size_t)row * 128 + col0) = o0;
      *(float4*)(H + (size_t)row * 128 + col0 + 4) = o1;
    }
  }
}

// Aggregate: HALF-wave (32 lanes) per node, lane = 4 channels (float4).
// Metadata loaded 32-at-a-time coalesced, broadcast via width-32 shfl.
// 4 independent accumulators; 2 nodes/wave -> 8 gathers in flight per wave.
__global__ __launch_bounds__(256) void aggregate_kernel(
    const float* __restrict__ H, const int* __restrict__ ptr,
    const int* __restrict__ csrc, const float* __restrict__ cnorm,
    float* __restrict__ Xout, int n) {
  int node = blockIdx.x * 8 + (threadIdx.x >> 5);
  if (node >= n) return;
  int hl = threadIdx.x & 31;
  int beg = ptr[node], end = ptr[node + 1];
  float4 a0 = {0.f, 0.f, 0.f, 0.f}, a1 = a0, a2 = a0, a3 = a0;
  const float* Hc = H + hl * 4;
  for (int base = beg; base < end; base += 32) {
    int m = end - base;
    if (m > 32) m = 32;
    int idx = base + hl;
    int sl = (hl < m) ? csrc[idx] : 0;
    float nl = (hl < m) ? cnorm[idx] : 0.f;
    int j = 0;
    for (; j + 3 < m; j += 4) {
      int s0 = __shfl(sl, j, 32), s1 = __shfl(sl, j + 1, 32);
      int s2 = __shfl(sl, j + 2, 32), s3 = __shfl(sl, j + 3, 32);
      float n0 = __shfl(nl, j, 32), n1 = __shfl(nl, j + 1, 32);
      float n2 = __shfl(nl, j + 2, 32), n3 = __shfl(nl, j + 3, 32);
      float4 h0 = *(const float4*)(Hc + (size_t)s0 * 128);
      float4 h1 = *(const float4*)(Hc + (size_t)s1 * 128);
      float4 h2 = *(const float4*)(Hc + (size_t)s2 * 128);
      float4 h3 = *(const float4*)(Hc + (size_t)s3 * 128);
      a0.x = fmaf(h0.x, n0, a0.x); a0.y = fmaf(h0.y, n0, a0.y);
      a0.z = fmaf(h0.z, n0, a0.z); a0.w = fmaf(h0.w, n0, a0.w);
      a1.x = fmaf(h1.x, n1, a1.x); a1.y = fmaf(h1.y, n1, a1.y);
      a1.z = fmaf(h1.z, n1, a1.z); a1.w = fmaf(h1.w, n1, a1.w);
      a2.x = fmaf(h2.x, n2, a2.x); a2.y = fmaf(h2.y, n2, a2.y);
      a2.z = fmaf(h2.z, n2, a2.z); a2.w = fmaf(h2.w, n2, a2.w);
      a3.x = fmaf(h3.x, n3, a3.x); a3.y = fmaf(h3.y, n3, a3.y);
      a3.z = fmaf(h3.z, n3, a3.z); a3.w = fmaf(h3.w, n3, a3.w);
    }
    for (; j < m; ++j) {
      int s0 = __shfl(sl, j, 32);
      float n0 = __shfl(nl, j, 32);
      float4 h0 = *(const float4*)(Hc + (size_t)s0 * 128);
      a0.x = fmaf(h0.x, n0, a0.x); a0.y = fmaf(h0.y, n0, a0.y);
      a0.z = fmaf(h0.z, n0, a0.z); a0.w = fmaf(h0.w, n0, a0.w);
    }
  }
  float4 o;
  o.x = fmaxf((a0.x + a1.x) + (a2.x + a3.x), 0.f);
  o.y = fmaxf((a0.y + a1.y) + (a2.y + a3.y), 0.f);
  o.z = fmaxf((a0.z + a1.z) + (a2.z + a3.z), 0.f);
  o.w = fmaxf((a0.w + a1.w) + (a2.w + a3.w), 0.f);
  *(float4*)(Xout + (size_t)node * 128 + hl * 4) = o;
}

// Pool (segment-mean over sorted batch, atomic-free) + MLP head, fused.
// One block of 128 threads per graph.
__global__ __launch_bounds__(128) void pool_head_kernel(
    const float* __restrict__ X, const int* __restrict__ gptr,
    const float* __restrict__ Wp1, const float* __restrict__ bp1,
    const float* __restrict__ Wp2, const float* __restrict__ bp2,
    float* __restrict__ out, int G) {
  int g = blockIdx.x;
  int j = threadIdx.x;
  int beg = gptr[g], end = gptr[g + 1];
  __shared__ float ps[128];
  __shared__ float hs[128];
  float s0 = 0.f, s1 = 0.f, s2 = 0.f, s3 = 0.f;
  int i = beg;
  for (; i + 3 < end; i += 4) {
    s0 += X[(size_t)i * 128 + j];
    s1 += X[(size_t)(i + 1) * 128 + j];
    s2 += X[(size_t)(i + 2) * 128 + j];
    s3 += X[(size_t)(i + 3) * 128 + j];
  }
  for (; i < end; ++i) s0 += X[(size_t)i * 128 + j];
  float inv = 1.0f / (float)max(end - beg, 1);
  ps[j] = ((s0 + s1) + (s2 + s3)) * inv;
  __syncthreads();
  float acc = bp1[j];
#pragma unroll 8
  for (int k = 0; k < 128; ++k) acc = fmaf(ps[k], Wp1[k * 128 + j], acc);
  hs[j] = fmaxf(acc, 0.f) * Wp2[j];
  __syncthreads();
  for (int off = 64; off > 0; off >>= 1) {
    if (j < off) hs[j] += hs[j + off];
    __syncthreads();
  }
  if (j == 0) out[g] = hs[0] + bp2[0];
}

extern "C" void kernel_launch(void* const* d_in, const int* in_sizes, int n_in,
                              void* d_out, int out_size, void* d_ws, size_t ws_size,
                              hipStream_t stream) {
  const float* x    = (const float*)d_in[0];
  const int*   eidx = (const int*)d_in[1];
  const int*   batch= (const int*)d_in[2];
  const float* W0 = (const float*)d_in[3];
  const float* b0 = (const float*)d_in[4];
  const float* W1 = (const float*)d_in[5];
  const float* b1 = (const float*)d_in[6];
  const float* W2 = (const float*)d_in[7];
  const float* b2 = (const float*)d_in[8];
  const float* Wp1 = (const float*)d_in[9];
  const float* bp1 = (const float*)d_in[10];
  const float* Wp2 = (const float*)d_in[11];
  const float* bp2 = (const float*)d_in[12];
  float* out = (float*)d_out;

  const int N = in_sizes[0] / 128;
  const int E = in_sizes[1] / 2;
  const int G = out_size;
  const int M = E + N;
  const int T = (N + 1023) / 1024;  // #scan tiles; N<=131072 keeps T<=128

  const int* src = eidx;
  const int* dst = eidx + E;

  char* ws = (char*)d_ws;
  size_t off = 0;
  auto alloc = [&](size_t bytes) -> void* {
    void* p = ws + off;
    off = (off + bytes + 255) & ~(size_t)255;
    return p;
  };
  int*   indeg   = (int*)  alloc((size_t)N * 4);
  int*   ptr     = (int*)  alloc((size_t)(N + 1) * 4);
  int*   cursor  = (int*)  alloc((size_t)N * 4);
  int*   csrc    = (int*)  alloc((size_t)M * 4);
  float* cnorm   = (float*)alloc((size_t)M * 4);
  float* bufH    = (float*)alloc((size_t)N * 128 * 4);
  float* bufX    = (float*)alloc((size_t)N * 128 * 4);
  int*   gptr    = (int*)  alloc((size_t)(G + 1) * 4);
  int*   tilesum = (int*)  alloc((size_t)T * 4);
  int*   tileoff = (int*)  alloc((size_t)T * 4);
  (void)ws_size;

  hipMemsetAsync(indeg,  0, (size_t)N * 4, stream);
  hipMemsetAsync(cursor, 0, (size_t)N * 4, stream);

  count_deg_kernel<<<(E + 255) / 256, 256, 0, stream>>>(dst, indeg, E);
  tile_reduce_kernel<<<T, 1024, 0, stream>>>(indeg, tilesum, N);
  scan_tiles_kernel<<<1, 128, 0, stream>>>(tilesum, tileoff, ptr + N, T);
  scan_emit_kernel<<<T, 1024, 0, stream>>>(indeg, tileoff, ptr, N);
  fill_edges_kernel<<<(E + 255) / 256, 256, 0, stream>>>(src, dst, indeg, ptr, cursor, csrc, cnorm, E);
  fill_self_kernel<<<(N + 255) / 256, 256, 0, stream>>>(indeg, ptr, cursor, csrc, cnorm, N);
  graph_bounds_kernel<<<(N + 255) / 256, 256, 0, stream>>>(batch, gptr, N, G);

  dim3 gemm_grid((N + 63) / 64);
  dim3 agg_grid((N + 7) / 8);

  gemm_bias_kernel<<<gemm_grid, 256, 0, stream>>>(x,    W0, b0, bufH, N);
  aggregate_kernel<<<agg_grid, 256, 0, stream>>>(bufH, ptr, csrc, cnorm, bufX, N);
  gemm_bias_kernel<<<gemm_grid, 256, 0, stream>>>(bufX, W1, b1, bufH, N);
  aggregate_kernel<<<agg_grid, 256, 0, stream>>>(bufH, ptr, csrc, cnorm, bufX, N);
  gemm_bias_kernel<<<gemm_grid, 256, 0, stream>>>(bufX, W2, b2, bufH, N);
  aggregate_kernel<<<agg_grid, 256, 0, stream>>>(bufH, ptr, csrc, cnorm, bufX, N);

  pool_head_kernel<<<G, 128, 0, stream>>>(bufX, gptr, Wp1, bp1, Wp2, bp2, out, G);
}